// Round 3
// baseline (35.754 us; speedup 1.0000x reference)
//
#include <hip/hip_runtime.h>

// Fasttext: out[b,t,p] = W @ embed[ids[b,t]] + b, masked t < seq_lengths[b]
// VOCAB=200000, E=300 (pad->320), P=128, B=16, S=2048, BS=32768
//
// R2 design (resubmit after infra failure): no LDS, no barriers. 512 blocks
// x 256 threads. Each wave owns 16 tokens x all 128 output cols: A-fragments
// loaded straight from embed (2x float4 per k-step, packed to bf16x8
// in-register), B from bf16 Wb in d_ws. 20 independent gather loads/lane ->
// latency hidden by ILP instead of a serial 16-row staging loop.

#define VOCAB 200000
#define E 300
#define EP 320          // padded K (10 * 32); Wb zero-padded 300..319
#define P 128
#define S 2048
#define BS 32768
#define TM 64           // tokens per block tile

typedef short bf16x8 __attribute__((ext_vector_type(8)));
typedef float f32x4 __attribute__((ext_vector_type(4)));

__device__ inline unsigned short f32_bf16_rne(float f) {
    unsigned int u = __builtin_bit_cast(unsigned int, f);
    unsigned int r = u + 0x7FFFu + ((u >> 16) & 1u);
    return (unsigned short)(r >> 16);
}
// hot-path pack: round-nearest (ties up) — 2 VALU/elem
__device__ inline unsigned short f32_bf16_fast(float f) {
    unsigned int u = __builtin_bit_cast(unsigned int, f);
    return (unsigned short)((u + 0x8000u) >> 16);
}
__device__ inline bf16x8 cvt8(f32x4 a, f32x4 b) {
    bf16x8 r;
    r[0] = (short)f32_bf16_fast(a[0]); r[1] = (short)f32_bf16_fast(a[1]);
    r[2] = (short)f32_bf16_fast(a[2]); r[3] = (short)f32_bf16_fast(a[3]);
    r[4] = (short)f32_bf16_fast(b[0]); r[5] = (short)f32_bf16_fast(b[1]);
    r[6] = (short)f32_bf16_fast(b[2]); r[7] = (short)f32_bf16_fast(b[3]);
    return r;
}

// prep: W [128][300] f32 -> Wb [128][320] bf16, zero-padded K (RNE)
__global__ void ft_wprep(const float* __restrict__ W, unsigned short* __restrict__ Wb) {
    int i = blockIdx.x * 256 + threadIdx.x;
    if (i >= P * EP) return;
    int p = i / EP, e = i - p * EP;
    float v = (e < E) ? W[p * E + e] : 0.0f;
    Wb[i] = f32_bf16_rne(v);
}

template <bool USE_WS>
__global__ __launch_bounds__(256) void ft_main(
    const int* __restrict__ ids, const int* __restrict__ seqlen,
    const float* __restrict__ embed, const unsigned short* __restrict__ Wb,
    const float* __restrict__ Wf, const float* __restrict__ bias,
    float* __restrict__ out)
{
    const int tid = threadIdx.x;
    const int wave = tid >> 6, lane = tid & 63;
    const int tok0 = blockIdx.x * TM;

    // ---- full-tile mask early-out (tile lies within one batch: 64 | 2048) ----
    const int bi0 = tok0 >> 11;
    const int t0  = tok0 & (S - 1);
    const int sl0 = seqlen[bi0];
    if (sl0 <= t0) {
        f32x4* o = (f32x4*)(out + (long long)tok0 * P);
        f32x4 z = {0.f, 0.f, 0.f, 0.f};
        #pragma unroll
        for (int i = 0; i < (TM * P / 4) / 256; ++i)
            o[tid + i * 256] = z;
        return;
    }

    const int fr = lane & 15, kg = lane >> 4;

    // this lane's A row (token) for fragment loads
    const int token_a = tok0 + wave * 16 + fr;
    const long long id = ids[token_a];
    const float* __restrict__ rp = embed + id * (long long)E;

    f32x4 acc[8];
    #pragma unroll
    for (int ni = 0; ni < 8; ++ni) acc[ni] = (f32x4){0.f, 0.f, 0.f, 0.f};

    // ---- 9 full k-steps (k = 0..287, all < 300: in-bounds, 16B-aligned) ----
    #pragma unroll 3
    for (int k0 = 0; k0 < 288; k0 += 32) {
        const int kb = k0 + kg * 8;
        f32x4 f0 = *(const f32x4*)(rp + kb);
        f32x4 f1 = *(const f32x4*)(rp + kb + 4);
        bf16x8 av = cvt8(f0, f1);
        #pragma unroll
        for (int ni = 0; ni < 8; ++ni) {
            bf16x8 bv;
            if constexpr (USE_WS) {
                bv = *(const bf16x8*)&Wb[(ni * 16 + fr) * EP + kb];
            } else {
                const float* wr = Wf + (long long)(ni * 16 + fr) * E + kb;
                f32x4 w0 = *(const f32x4*)(wr);
                f32x4 w1 = *(const f32x4*)(wr + 4);
                bv = cvt8(w0, w1);
            }
            acc[ni] = __builtin_amdgcn_mfma_f32_16x16x32_bf16(av, bv, acc[ni], 0, 0, 0);
        }
    }

    // ---- tail k-step k0=288 (k = 288..319; guard k<300, Wb pad is zero) ----
    {
        float tv[8];
        #pragma unroll
        for (int j = 0; j < 8; ++j) {
            int k = 288 + kg * 8 + j;
            tv[j] = (k < E) ? rp[k] : 0.0f;
        }
        f32x4 f0 = {tv[0], tv[1], tv[2], tv[3]};
        f32x4 f1 = {tv[4], tv[5], tv[6], tv[7]};
        bf16x8 av = cvt8(f0, f1);
        #pragma unroll
        for (int ni = 0; ni < 8; ++ni) {
            bf16x8 bv;
            if constexpr (USE_WS) {
                bv = *(const bf16x8*)&Wb[(ni * 16 + fr) * EP + 288 + kg * 8];
            } else {
                const float* wr = Wf + (long long)(ni * 16 + fr) * E;
                float wv[8];
                #pragma unroll
                for (int j = 0; j < 8; ++j) {
                    int k = 288 + kg * 8 + j;
                    wv[j] = (k < E) ? wr[k] : 0.0f;
                }
                f32x4 w0 = {wv[0], wv[1], wv[2], wv[3]};
                f32x4 w1 = {wv[4], wv[5], wv[6], wv[7]};
                bv = cvt8(w0, w1);
            }
            acc[ni] = __builtin_amdgcn_mfma_f32_16x16x32_bf16(av, bv, acc[ni], 0, 0, 0);
        }
    }

    // ---- epilogue: +bias, per-row seq-mask, store ----
    // C/D layout: col(=P dim) = lane&15, row(=token dim) = (lane>>4)*4 + j
    float bs[8];
    #pragma unroll
    for (int ni = 0; ni < 8; ++ni) bs[ni] = bias[ni * 16 + fr];

    #pragma unroll
    for (int j = 0; j < 4; ++j) {
        int orow  = wave * 16 + kg * 4 + j;
        int token = tok0 + orow;
        int t     = token & (S - 1);
        bool valid = (t < sl0);
        #pragma unroll
        for (int ni = 0; ni < 8; ++ni) {
            float v = valid ? (acc[ni][j] + bs[ni]) : 0.0f;
            out[(long long)token * P + ni * 16 + fr] = v;
        }
    }
}

extern "C" void kernel_launch(void* const* d_in, const int* in_sizes, int n_in,
                              void* d_out, int out_size, void* d_ws, size_t ws_size,
                              hipStream_t stream) {
    const int*   ids    = (const int*)d_in[0];
    const int*   sl     = (const int*)d_in[1];
    const float* embed  = (const float*)d_in[2];
    const float* W      = (const float*)d_in[3];
    const float* bias   = (const float*)d_in[4];
    float*       out    = (float*)d_out;

    const size_t wb_bytes = (size_t)P * EP * 2;
    if (ws_size >= wb_bytes) {
        unsigned short* Wb = (unsigned short*)d_ws;
        ft_wprep<<<(P * EP + 255) / 256, 256, 0, stream>>>(W, Wb);
        ft_main<true><<<BS / TM, 256, 0, stream>>>(ids, sl, embed, Wb, W, bias, out);
    } else {
        ft_main<false><<<BS / TM, 256, 0, stream>>>(ids, sl, embed, nullptr, W, bias, out);
    }
}

// Round 4
// 35.401 us; speedup vs baseline: 1.0100x; 1.0100x over previous
//
#include <hip/hip_runtime.h>

// Fasttext: out[b,t,p] = W @ embed[ids[b,t]] + b, masked t < seq_lengths[b]
// VOCAB=200000, E=300 (pad->320), P=128, B=16, S=2048, BS=32768
//
// R4: attack gather-latency exposure. TM=32, 1024 blocks x 256 thr; each
// wave owns 16 tokens x 64 cols (2-way N split -> 4096 waves, 16 waves/CU
// via __launch_bounds__(256,4)). All 10 k-steps of A loaded+converted up
// front (av[10] = 40 VGPRs) -> ~20 independent gather loads in flight per
// lane. B from pre-converted bf16 Wb (d_ws, L1/L2-hot). Exact-bounds tail.

#define VOCAB 200000
#define E 300
#define EP 320          // padded K (10 * 32); Wb zero-padded 300..319
#define P 128
#define S 2048
#define BS 32768
#define TM 32           // tokens per block tile

typedef short bf16x8 __attribute__((ext_vector_type(8)));
typedef float f32x4 __attribute__((ext_vector_type(4)));

__device__ inline unsigned short f32_bf16_rne(float f) {
    unsigned int u = __builtin_bit_cast(unsigned int, f);
    unsigned int r = u + 0x7FFFu + ((u >> 16) & 1u);
    return (unsigned short)(r >> 16);
}
// hot-path pack: round-nearest (ties up) — 2 VALU/elem
__device__ inline unsigned short f32_bf16_fast(float f) {
    unsigned int u = __builtin_bit_cast(unsigned int, f);
    return (unsigned short)((u + 0x8000u) >> 16);
}
__device__ inline bf16x8 cvt8(f32x4 a, f32x4 b) {
    bf16x8 r;
    r[0] = (short)f32_bf16_fast(a[0]); r[1] = (short)f32_bf16_fast(a[1]);
    r[2] = (short)f32_bf16_fast(a[2]); r[3] = (short)f32_bf16_fast(a[3]);
    r[4] = (short)f32_bf16_fast(b[0]); r[5] = (short)f32_bf16_fast(b[1]);
    r[6] = (short)f32_bf16_fast(b[2]); r[7] = (short)f32_bf16_fast(b[3]);
    return r;
}

// prep: W [128][300] f32 -> Wb [128][320] bf16, zero-padded K (RNE)
__global__ void ft_wprep(const float* __restrict__ W, unsigned short* __restrict__ Wb) {
    int i = blockIdx.x * 256 + threadIdx.x;
    if (i >= P * EP) return;
    int p = i / EP, e = i - p * EP;
    float v = (e < E) ? W[p * E + e] : 0.0f;
    Wb[i] = f32_bf16_rne(v);
}

template <bool USE_WS>
__global__ __launch_bounds__(256, 4) void ft_main(
    const int* __restrict__ ids, const int* __restrict__ seqlen,
    const float* __restrict__ embed, const unsigned short* __restrict__ Wb,
    const float* __restrict__ Wf, const float* __restrict__ bias,
    float* __restrict__ out)
{
    const int tid = threadIdx.x;
    const int wave = tid >> 6, lane = tid & 63;
    const int wm = wave >> 1, wn = wave & 1;       // token-half / col-half
    const int tok0 = blockIdx.x * TM;

    // ---- full-tile mask early-out (tile within one batch: 32 | 2048) ----
    const int bi0 = tok0 >> 11;
    const int t0  = tok0 & (S - 1);
    const int sl0 = seqlen[bi0];
    if (sl0 <= t0) {
        f32x4* o = (f32x4*)(out + (long long)tok0 * P);
        f32x4 z = {0.f, 0.f, 0.f, 0.f};
        #pragma unroll
        for (int i = 0; i < (TM * P / 4) / 256; ++i)
            o[tid + i * 256] = z;
        return;
    }

    const int fr = lane & 15, kg = lane >> 4;

    // this lane's A row (token)
    const int token_a = tok0 + wm * 16 + fr;
    const long long id = ids[token_a];
    const float* __restrict__ rp = embed + id * (long long)E;

    // ---- load + convert ALL A fragments up front (max loads in flight) ----
    bf16x8 av[10];
    #pragma unroll
    for (int s = 0; s < 9; ++s) {
        const int kb = s * 32 + kg * 8;            // <= 280; f1 ends at 287
        f32x4 f0 = *(const f32x4*)(rp + kb);
        f32x4 f1 = *(const f32x4*)(rp + kb + 4);
        av[s] = cvt8(f0, f1);
    }
    {   // tail step k0=288: valid k 288..299, exact bounds (no OOB reads)
        f32x4 z4 = {0.f, 0.f, 0.f, 0.f};
        f32x4 f0 = z4, f1 = z4;
        if (kg == 0)      { f0 = *(const f32x4*)(rp + 288); f1 = *(const f32x4*)(rp + 292); }
        else if (kg == 1) { f0 = *(const f32x4*)(rp + 296); }
        av[9] = cvt8(f0, f1);
    }

    f32x4 acc[4];
    #pragma unroll
    for (int ni = 0; ni < 4; ++ni) acc[ni] = (f32x4){0.f, 0.f, 0.f, 0.f};

    // ---- MFMA loop: 10 k-steps x 4 ni (wave's 64-col half) ----
    #pragma unroll
    for (int s = 0; s < 10; ++s) {
        const int kb = s * 32 + kg * 8;
        #pragma unroll
        for (int ni = 0; ni < 4; ++ni) {
            const int brow = wn * 64 + ni * 16 + fr;
            bf16x8 bv;
            if constexpr (USE_WS) {
                bv = *(const bf16x8*)&Wb[brow * EP + kb];
            } else {
                const float* wr = Wf + (long long)brow * E;
                float wv[8];
                #pragma unroll
                for (int j = 0; j < 8; ++j) {
                    int k = kb + j;
                    wv[j] = (k < E) ? wr[k] : 0.0f;
                }
                f32x4 w0 = {wv[0], wv[1], wv[2], wv[3]};
                f32x4 w1 = {wv[4], wv[5], wv[6], wv[7]};
                bv = cvt8(w0, w1);
            }
            acc[ni] = __builtin_amdgcn_mfma_f32_16x16x32_bf16(av[s], bv, acc[ni], 0, 0, 0);
        }
    }

    // ---- epilogue: +bias, per-row seq-mask, store ----
    // C/D layout: col(=P) = lane&15, row(=token) = (lane>>4)*4 + j
    float bs[4];
    #pragma unroll
    for (int ni = 0; ni < 4; ++ni) bs[ni] = bias[wn * 64 + ni * 16 + fr];

    #pragma unroll
    for (int j = 0; j < 4; ++j) {
        int orow  = wm * 16 + kg * 4 + j;
        int token = tok0 + orow;
        int t     = token & (S - 1);
        bool valid = (t < sl0);
        #pragma unroll
        for (int ni = 0; ni < 4; ++ni) {
            float v = valid ? (acc[ni][j] + bs[ni]) : 0.0f;
            out[(long long)token * P + wn * 64 + ni * 16 + fr] = v;
        }
    }
}

extern "C" void kernel_launch(void* const* d_in, const int* in_sizes, int n_in,
                              void* d_out, int out_size, void* d_ws, size_t ws_size,
                              hipStream_t stream) {
    const int*   ids    = (const int*)d_in[0];
    const int*   sl     = (const int*)d_in[1];
    const float* embed  = (const float*)d_in[2];
    const float* W      = (const float*)d_in[3];
    const float* bias   = (const float*)d_in[4];
    float*       out    = (float*)d_out;

    const size_t wb_bytes = (size_t)P * EP * 2;
    if (ws_size >= wb_bytes) {
        unsigned short* Wb = (unsigned short*)d_ws;
        ft_wprep<<<(P * EP + 255) / 256, 256, 0, stream>>>(W, Wb);
        ft_main<true><<<BS / TM, 256, 0, stream>>>(ids, sl, embed, Wb, W, bias, out);
    } else {
        ft_main<false><<<BS / TM, 256, 0, stream>>>(ids, sl, embed, nullptr, W, bias, out);
    }
}

// Round 6
// 33.851 us; speedup vs baseline: 1.0562x; 1.0458x over previous
//
#include <hip/hip_runtime.h>

// Fasttext: out[b,t,p] = W @ embed[ids[b,t]] + b, masked t < seq_lengths[b]
// VOCAB=200000, E=300, P=128, B=16, S=2048, BS=32768
//
// R5 (resubmit after infra failure): SINGLE-LAUNCH probe. R2-R4 showed
// dur_us invariant (35.4us) across radically different schedules -> suspect
// per-launch/graph overhead from the two-kernel graph. This round: one
// kernel only. W loaded as f32, converted to bf16 in-register (153KB,
// L2-hot after first block). Same MFMA structure as R4: TM=32, 1024 blocks,
// wave = 16 tokens x 64 cols, all A-gather loads hoisted. Exact-bounds
// tails everywhere (no OOB).

#define VOCAB 200000
#define E 300
#define P 128
#define S 2048
#define BS 32768
#define TM 32           // tokens per block tile

typedef short bf16x8 __attribute__((ext_vector_type(8)));
typedef float f32x4 __attribute__((ext_vector_type(4)));

// round-nearest (ties up) f32->bf16: 2 VALU/elem
__device__ inline unsigned short f32_bf16_fast(float f) {
    unsigned int u = __builtin_bit_cast(unsigned int, f);
    return (unsigned short)((u + 0x8000u) >> 16);
}
__device__ inline bf16x8 cvt8(f32x4 a, f32x4 b) {
    bf16x8 r;
    r[0] = (short)f32_bf16_fast(a[0]); r[1] = (short)f32_bf16_fast(a[1]);
    r[2] = (short)f32_bf16_fast(a[2]); r[3] = (short)f32_bf16_fast(a[3]);
    r[4] = (short)f32_bf16_fast(b[0]); r[5] = (short)f32_bf16_fast(b[1]);
    r[6] = (short)f32_bf16_fast(b[2]); r[7] = (short)f32_bf16_fast(b[3]);
    return r;
}

__global__ __launch_bounds__(256, 4) void ft_main(
    const int* __restrict__ ids, const int* __restrict__ seqlen,
    const float* __restrict__ embed, const float* __restrict__ Wf,
    const float* __restrict__ bias, float* __restrict__ out)
{
    const int tid = threadIdx.x;
    const int wave = tid >> 6, lane = tid & 63;
    const int wm = wave >> 1, wn = wave & 1;       // token-half / col-half
    const int tok0 = blockIdx.x * TM;

    // ---- full-tile mask early-out (tile within one batch: 32 | 2048) ----
    const int bi0 = tok0 >> 11;
    const int t0  = tok0 & (S - 1);
    const int sl0 = seqlen[bi0];
    if (sl0 <= t0) {
        f32x4* o = (f32x4*)(out + (long long)tok0 * P);
        f32x4 z = {0.f, 0.f, 0.f, 0.f};
        #pragma unroll
        for (int i = 0; i < (TM * P / 4) / 256; ++i)
            o[tid + i * 256] = z;
        return;
    }

    const int fr = lane & 15, kg = lane >> 4;

    // this lane's A row (token)
    const int token_a = tok0 + wm * 16 + fr;
    const long long id = ids[token_a];
    const float* __restrict__ rp = embed + id * (long long)E;

    // ---- load + convert ALL A fragments up front (max loads in flight) ----
    bf16x8 av[10];
    #pragma unroll
    for (int s = 0; s < 9; ++s) {
        const int kb = s * 32 + kg * 8;            // <= 280; ends at 287 < 300
        f32x4 f0 = *(const f32x4*)(rp + kb);
        f32x4 f1 = *(const f32x4*)(rp + kb + 4);
        av[s] = cvt8(f0, f1);
    }
    {   // tail k-step: valid k 288..299, exact bounds (row ends at 300)
        f32x4 z4 = {0.f, 0.f, 0.f, 0.f};
        f32x4 f0 = z4, f1 = z4;
        if (kg == 0)      { f0 = *(const f32x4*)(rp + 288); f1 = *(const f32x4*)(rp + 292); }
        else if (kg == 1) { f0 = *(const f32x4*)(rp + 296); }   // 296..299 exact
        av[9] = cvt8(f0, f1);
    }

    f32x4 acc[4];
    #pragma unroll
    for (int ni = 0; ni < 4; ++ni) acc[ni] = (f32x4){0.f, 0.f, 0.f, 0.f};

    // ---- MFMA loop: 10 k-steps x 4 ni; B = W rows converted in-register ----
    #pragma unroll
    for (int s = 0; s < 9; ++s) {
        const int kb = s * 32 + kg * 8;
        #pragma unroll
        for (int ni = 0; ni < 4; ++ni) {
            const float* wr = Wf + (long long)(wn * 64 + ni * 16 + fr) * E + kb;
            f32x4 w0 = *(const f32x4*)(wr);
            f32x4 w1 = *(const f32x4*)(wr + 4);
            acc[ni] = __builtin_amdgcn_mfma_f32_16x16x32_bf16(av[s], cvt8(w0, w1),
                                                              acc[ni], 0, 0, 0);
        }
    }
    {   // tail k-step for B: k 288..299 valid, zero-pad 300..319, exact bounds
        #pragma unroll
        for (int ni = 0; ni < 4; ++ni) {
            const float* wr = Wf + (long long)(wn * 64 + ni * 16 + fr) * E;
            f32x4 z4 = {0.f, 0.f, 0.f, 0.f};
            f32x4 w0 = z4, w1 = z4;
            if (kg == 0)      { w0 = *(const f32x4*)(wr + 288); w1 = *(const f32x4*)(wr + 292); }
            else if (kg == 1) { w0 = *(const f32x4*)(wr + 296); }  // 296..299 exact
            acc[ni] = __builtin_amdgcn_mfma_f32_16x16x32_bf16(av[9], cvt8(w0, w1),
                                                              acc[ni], 0, 0, 0);
        }
    }

    // ---- epilogue: +bias, per-row seq-mask, store ----
    // C/D layout: col(=P) = lane&15, row(=token) = (lane>>4)*4 + j
    float bs[4];
    #pragma unroll
    for (int ni = 0; ni < 4; ++ni) bs[ni] = bias[wn * 64 + ni * 16 + fr];

    #pragma unroll
    for (int j = 0; j < 4; ++j) {
        int orow  = wm * 16 + kg * 4 + j;
        int token = tok0 + orow;
        int t     = token & (S - 1);
        bool valid = (t < sl0);
        #pragma unroll
        for (int ni = 0; ni < 4; ++ni) {
            float v = valid ? (acc[ni][j] + bs[ni]) : 0.0f;
            out[(long long)token * P + wn * 64 + ni * 16 + fr] = v;
        }
    }
}

extern "C" void kernel_launch(void* const* d_in, const int* in_sizes, int n_in,
                              void* d_out, int out_size, void* d_ws, size_t ws_size,
                              hipStream_t stream) {
    const int*   ids    = (const int*)d_in[0];
    const int*   sl     = (const int*)d_in[1];
    const float* embed  = (const float*)d_in[2];
    const float* W      = (const float*)d_in[3];
    const float* bias   = (const float*)d_in[4];
    float*       out    = (float*)d_out;

    ft_main<<<BS / TM, 256, 0, stream>>>(ids, sl, embed, W, bias, out);
}

// Round 8
// 22.734 us; speedup vs baseline: 1.5727x; 1.4890x over previous
//
#include <hip/hip_runtime.h>

// Fasttext: out[b,t,p] = W @ embed[ids[b,t]] + b, masked t < seq_lengths[b]
// VOCAB=200000, E=300, P=128, B=16, S=2048, BS=32768
//
// R7 (resubmit after infra failure): kill strided W re-reads (the invariant
// across R1-R6). Single launch. Block = 64 tokens x 64-col half (grid 1024 =
// 512 tiles x 2 halves), 256 thr / 4 waves; wave = 16 tokens x 64 cols.
// W-half staged ONCE per block into LDS as bf16 FRAGMENT-MAJOR (40960 B):
// fragment (s,ni) is 16 lanes x 64B contiguous, so each B-read is one
// conflict-free ds_read_b128 (64 lanes x contiguous 16B = 1KB). Staging
// reads W dense+coalesced. A-gather per lane hoisted (19 independent
// loads). Exact-bounds tails. LDS 40KB -> 4 blocks/CU.

#define E 300
#define P 128
#define S 2048
#define BS 32768
#define TM 64           // tokens per block tile

typedef short bf16x8 __attribute__((ext_vector_type(8)));
typedef short bf16x4 __attribute__((ext_vector_type(4)));
typedef float f32x4 __attribute__((ext_vector_type(4)));

// round-nearest (ties up) f32->bf16: 2 VALU/elem
__device__ inline unsigned short f32_bf16_fast(float f) {
    unsigned int u = __builtin_bit_cast(unsigned int, f);
    return (unsigned short)((u + 0x8000u) >> 16);
}
__device__ inline bf16x8 cvt8(f32x4 a, f32x4 b) {
    bf16x8 r;
    r[0] = (short)f32_bf16_fast(a[0]); r[1] = (short)f32_bf16_fast(a[1]);
    r[2] = (short)f32_bf16_fast(a[2]); r[3] = (short)f32_bf16_fast(a[3]);
    r[4] = (short)f32_bf16_fast(b[0]); r[5] = (short)f32_bf16_fast(b[1]);
    r[6] = (short)f32_bf16_fast(b[2]); r[7] = (short)f32_bf16_fast(b[3]);
    return r;
}
__device__ inline bf16x4 cvt4(f32x4 a) {
    bf16x4 r;
    r[0] = (short)f32_bf16_fast(a[0]); r[1] = (short)f32_bf16_fast(a[1]);
    r[2] = (short)f32_bf16_fast(a[2]); r[3] = (short)f32_bf16_fast(a[3]);
    return r;
}

__global__ __launch_bounds__(256) void ft_main(
    const int* __restrict__ ids, const int* __restrict__ seqlen,
    const float* __restrict__ embed, const float* __restrict__ Wf,
    const float* __restrict__ bias, float* __restrict__ out)
{
    // W-half, bf16, fragment-major: offset((s,ni,fr,kg,h)) =
    //   ((s*4+ni)*16+fr)*64 + kg*16 + h*8   -> 10*4*16*64 = 40960 B
    __shared__ unsigned char Wl[40960];

    const int tid  = threadIdx.x;
    const int wave = tid >> 6, lane = tid & 63;
    const int fr   = lane & 15, kg = lane >> 4;

    const int tile = blockIdx.x >> 1;
    const int ch   = blockIdx.x & 1;            // which 64-col half of P
    const int tok0 = tile * TM;
    const int bi0  = tok0 >> 11;                // batch (64 | 2048)
    const int t0   = tok0 & (S - 1);
    const int sl0  = seqlen[bi0];

    // ---- full-tile mask early-out: zero 64 tokens x our 64-col half ----
    if (sl0 <= t0) {
        #pragma unroll
        for (int i = 0; i < 4; ++i) {
            int idx   = tid + i * 256;          // [0,1024): 64 tok x 16 col-quads
            int token = tok0 + (idx >> 4);
            int c     = ch * 64 + (idx & 15) * 4;
            *(f32x4*)(out + (long long)token * P + c) = (f32x4){0.f, 0.f, 0.f, 0.f};
        }
        return;
    }

    // ---- A: issue the gather early (independent of LDS staging) ----
    const int token_a = tok0 + wave * 16 + fr;
    const long long id = ids[token_a];
    const float* __restrict__ rp = embed + id * (long long)E;

    bf16x8 av[10];
    #pragma unroll
    for (int s = 0; s < 9; ++s) {
        const int kb = s * 32 + kg * 8;         // <= 280; ends 287 < 300
        f32x4 f0 = *(const f32x4*)(rp + kb);
        f32x4 f1 = *(const f32x4*)(rp + kb + 4);
        av[s] = cvt8(f0, f1);
    }
    {   // tail: valid k 288..299, exact bounds
        f32x4 z4 = {0.f, 0.f, 0.f, 0.f};
        f32x4 f0 = z4, f1 = z4;
        if (kg == 0)      { f0 = *(const f32x4*)(rp + 288); f1 = *(const f32x4*)(rp + 292); }
        else if (kg == 1) { f0 = *(const f32x4*)(rp + 296); }
        av[9] = cvt8(f0, f1);
    }

    // ---- stage W rows [ch*64, ch*64+64) -> LDS bf16 fragment-major ----
    // flat g4 in [0,5120): r = g4/80, c0 = (g4%80)*4 in [0,320); zero-pad c0>=300.
    const int R0 = ch * 64;
    #pragma unroll
    for (int i = 0; i < 20; ++i) {
        int g4 = tid + i * 256;
        int r  = g4 / 80;
        int c4 = g4 - r * 80;
        int c0 = c4 * 4;
        f32x4 v = {0.f, 0.f, 0.f, 0.f};
        if (c0 < 300)                            // c0 <= 296 -> reads 296..299, exact
            v = *(const f32x4*)(Wf + (long long)(R0 + r) * E + c0);
        int s   = c0 >> 5;
        int kgg = (c0 & 31) >> 3;
        int h   = (c0 >> 2) & 1;
        int ni  = r >> 4;
        int fr2 = r & 15;
        int off = (((s * 4 + ni) * 16 + fr2) << 6) + (kgg << 4) + (h << 3);
        *(bf16x4*)(Wl + off) = cvt4(v);
    }
    __syncthreads();

    // ---- MFMA: 10 k-steps x 4 ni, B from LDS (conflict-free b128) ----
    f32x4 acc[4];
    #pragma unroll
    for (int ni = 0; ni < 4; ++ni) acc[ni] = (f32x4){0.f, 0.f, 0.f, 0.f};

    #pragma unroll
    for (int s = 0; s < 10; ++s) {
        #pragma unroll
        for (int ni = 0; ni < 4; ++ni) {
            bf16x8 bv = *(const bf16x8*)(Wl + ((((s * 4 + ni) * 16 + fr) << 6) + (kg << 4)));
            acc[ni] = __builtin_amdgcn_mfma_f32_16x16x32_bf16(av[s], bv, acc[ni], 0, 0, 0);
        }
    }

    // ---- epilogue: +bias, per-row seq-mask, store ----
    // C/D layout: col(=W row -> P) = lane&15, row(=token) = (lane>>4)*4 + j
    float bs[4];
    #pragma unroll
    for (int ni = 0; ni < 4; ++ni) bs[ni] = bias[ch * 64 + ni * 16 + fr];

    #pragma unroll
    for (int j = 0; j < 4; ++j) {
        int orow  = wave * 16 + kg * 4 + j;
        int token = tok0 + orow;
        int t     = token & (S - 1);
        bool valid = (t < sl0);
        #pragma unroll
        for (int ni = 0; ni < 4; ++ni) {
            float v = valid ? (acc[ni][j] + bs[ni]) : 0.0f;
            out[(long long)token * P + ch * 64 + ni * 16 + fr] = v;
        }
    }
}

extern "C" void kernel_launch(void* const* d_in, const int* in_sizes, int n_in,
                              void* d_out, int out_size, void* d_ws, size_t ws_size,
                              hipStream_t stream) {
    const int*   ids    = (const int*)d_in[0];
    const int*   sl     = (const int*)d_in[1];
    const float* embed  = (const float*)d_in[2];
    const float* W      = (const float*)d_in[3];
    const float* bias   = (const float*)d_in[4];
    float*       out    = (float*)d_out;

    ft_main<<<(BS / TM) * 2, 256, 0, stream>>>(ids, sl, embed, W, bias, out);
}